// Round 5
// baseline (212.687 us; speedup 1.0000x reference)
//
#include <hip/hip_runtime.h>

#define GD    256
#define DIM   64
#define KCB   1024
#define KT    128    // codewords per tile
#define NROW  32768
#define NTOT  131072

typedef float floatx4 __attribute__((ext_vector_type(4)));
typedef __bf16 bf16x8 __attribute__((ext_vector_type(8)));
typedef unsigned int uint;

union ABu { bf16x8 v; __bf16 h[8]; uint4 u4; };
union B2u { __bf16 h[4]; uint2 u2; };

// ---------------------------------------------------------------------------
// Prep: latents fp32 -> bf16 (XOR-swizzled 16B chunks, [g][row] 128B rows),
// per-(g,row) x_sq, codebook fp32 -> bf16 swizzled + initv, keys=~0, loss=0.
// ---------------------------------------------------------------------------
extern "C" __global__ void __launch_bounds__(256)
vq_prep(const float* __restrict__ latents, const float* __restrict__ cbg,
        uint* __restrict__ lat_bf, uint* __restrict__ cb_bf,
        float* __restrict__ initv, uint* __restrict__ keys,
        float* __restrict__ xsq_g, float* __restrict__ loss)
{
    const int bid = blockIdx.x;
    if (bid < 8192) {                       // latents: thread per float4
        const int idx = bid * 256 + threadIdx.x;
        const float4 f = ((const float4*)latents)[idx];
        const int row = idx >> 6;
        const int c   = idx & 63;
        const int g   = c >> 4;
        const int c16 = c & 15;
        float d = f.x*f.x + f.y*f.y + f.z*f.z + f.w*f.w;
        d += __shfl_xor(d, 1);
        d += __shfl_xor(d, 2);
        d += __shfl_xor(d, 4);
        d += __shfl_xor(d, 8);
        B2u t;
        t.h[0]=(__bf16)f.x; t.h[1]=(__bf16)f.y; t.h[2]=(__bf16)f.z; t.h[3]=(__bf16)f.w;
        const int w = (g*NROW + row)*32 + (((c16>>1) ^ (row&7))<<2) + ((c16&1)<<1);
        *(uint2*)&lat_bf[w] = t.u2;
        if (c16 == 0) xsq_g[g*NROW + row] = d;
        if (c16 == 1) keys[g*NROW + row] = 0xFFFFFFFFu;
    } else {                                // codebook: thread per codeword row
        const int k = (bid - 8192) * 256 + threadIdx.x;   // 0..4095
        if (bid == 8192 && threadIdx.x == 0) *loss = 0.f;
        const float4* src = (const float4*)(cbg + (size_t)k * DIM);
        float csq = 0.f;
        #pragma unroll
        for (int j = 0; j < 16; ++j) {
            const float4 f = src[j];
            csq += f.x*f.x + f.y*f.y + f.z*f.z + f.w*f.w;
            B2u t;
            t.h[0]=(__bf16)f.x; t.h[1]=(__bf16)f.y; t.h[2]=(__bf16)f.z; t.h[3]=(__bf16)f.w;
            const int w = k*32 + (((j>>1) ^ (k&7))<<2) + ((j&1)<<1);
            *(uint2*)&cb_bf[w] = t.u2;
        }
        initv[k] = -0.5f * csq - 0.5f;      // makes every score < 0
    }
}

// ---------------------------------------------------------------------------
// Score: pure MFMA hot loop. Tile staged by global_load_lds DMA (pre-swizzled
// so identity lane-copy lands correctly). 32 rows/wave, 7 blocks/CU.
// bid bits: [2:0]=chunk-low (XCD spread), [5:3]=tile (siblings share XCD),
// [10:6]=chunk-high, [12:11]=g.
// ---------------------------------------------------------------------------
extern "C" __global__ void __launch_bounds__(256, 7)
vq_score(const uint* __restrict__ lat_bf, const uint* __restrict__ cb_bf,
         const float* __restrict__ initv, uint* __restrict__ keys)
{
    __shared__ __attribute__((aligned(16))) uint cb_lds[KT * 32];   // 16 KB

    const int tid  = threadIdx.x;
    const int wave = tid >> 6;
    const int lane = tid & 63;
    const int l15  = lane & 15;
    const int quad = lane >> 4;

    const int bid   = blockIdx.x;
    const int clo   = bid & 7;
    const int tile  = (bid >> 3) & 7;
    const int rest  = bid >> 6;
    const int chunk = ((rest & 31) << 3) | clo;   // 0..255
    const int g     = rest >> 5;

    // ---- async DMA: 16 KB codebook tile, zero VALU/cvt ----
    {
        const uint* gsrc = cb_bf + (size_t)(g * KCB + tile * KT) * 32;
        #pragma unroll
        for (int i = 0; i < 4; ++i) {
            const int off = wave * 1024 + i * 256;     // words
            __builtin_amdgcn_global_load_lds(
                (const __attribute__((address_space(1))) uint*)(gsrc + off + lane * 4),
                (__attribute__((address_space(3))) uint*)&cb_lds[off], 16, 0, 0);
        }
    }

    // ---- A fragments: direct bf16 16B loads (pre-converted, swizzled) ----
    const int wRow0 = chunk * 128 + wave * 32;
    bf16x8 afrag[2][2];
    const uint* abase = lat_bf + (size_t)(g * NROW + wRow0) * 32;
    #pragma unroll
    for (int rt = 0; rt < 2; ++rt)
        #pragma unroll
        for (int ks = 0; ks < 2; ++ks) {
            const int r = rt * 16 + l15;
            const int cidx = (ks * 4 + quad) ^ (l15 & 7);
            ABu a; a.u4 = *(const uint4*)&abase[r * 32 + cidx * 4];
            afrag[rt][ks] = a.v;
        }
    __syncthreads();

    uint best[2][4];
    #pragma unroll
    for (int rt = 0; rt < 2; ++rt)
        #pragma unroll
        for (int r = 0; r < 4; ++r) best[rt][r] = 0xFFFFFFFFu;

    const float* __restrict__ ivt = initv + g * KCB + tile * KT;
    #pragma unroll
    for (int t = 0; t < 8; ++t) {
        const int kkl = t * 16 + l15;
        const float v = ivt[kkl];                  // L1/L2-hot scalar
        ABu b0, b1;
        b0.u4 = *(const uint4*)&cb_lds[kkl * 32 + (((quad    ) ^ (kkl & 7)) << 2)];
        b1.u4 = *(const uint4*)&cb_lds[kkl * 32 + (((quad + 4) ^ (kkl & 7)) << 2)];
        const uint kcol = (uint)(tile * KT + kkl);
        const floatx4 accb = { v, v, v, v };       // shared C operand (D != C)
        #pragma unroll
        for (int rt = 0; rt < 2; ++rt) {
            floatx4 acc = __builtin_amdgcn_mfma_f32_16x16x32_bf16(afrag[rt][0], b0.v, accb, 0, 0, 0);
            acc = __builtin_amdgcn_mfma_f32_16x16x32_bf16(afrag[rt][1], b1.v, acc, 0, 0, 0);
            // score < 0 -> fp32 bits monotone decreasing; pack idx, min_u32
            #pragma unroll
            for (int r = 0; r < 4; ++r) {
                const uint key = (__float_as_uint(acc[r]) & 0xFFFFFC00u) | kcol;
                best[rt][r] = best[rt][r] < key ? best[rt][r] : key;
            }
        }
    }

    // ---- 16-lane column reduce, then cross-block atomicMin combine ----
    #pragma unroll
    for (int rt = 0; rt < 2; ++rt)
        #pragma unroll
        for (int r = 0; r < 4; ++r) {
            uint kmin = best[rt][r];
            #pragma unroll
            for (int m = 1; m <= 8; m <<= 1) {
                const uint o = (uint)__shfl_xor((int)kmin, m);
                kmin = o < kmin ? o : kmin;
            }
            if (l15 == 0)
                atomicMin(&keys[g * NROW + wRow0 + rt * 16 + quad * 4 + r], kmin);
        }
}

// ---------------------------------------------------------------------------
// Emit: wave = 16 rows x 4 groups (quad=group); dense 1 KB row writes.
// ---------------------------------------------------------------------------
extern "C" __global__ void __launch_bounds__(256, 4)
vq_emit(const uint* __restrict__ keys, const float* __restrict__ xsq_g,
        const float* __restrict__ cbg, float* __restrict__ out,
        float* __restrict__ loss)
{
    __shared__ float part[4];
    const int tid  = threadIdx.x;
    const int wave = tid >> 6;
    const int lane = tid & 63;
    const int l15  = lane & 15;
    const int quad = lane >> 4;          // group index
    const int n0   = blockIdx.x * 64 + wave * 16;

    const uint  key_l = keys [quad * NROW + n0 + l15];
    const float xsq_l = xsq_g[quad * NROW + n0 + l15];
    const float sc_l  = __uint_as_float(key_l & 0xFFFFFC00u);
    float lsum = xsq_l - 2.f * sc_l - 1.f;   // dist = x_sq - 2*score - 1

    const float4* __restrict__ cb4 = (const float4*)cbg;
    float4* __restrict__ out4 = (float4*)out;
    const int gbase = quad * (KCB * DIM / 4);
    #pragma unroll
    for (int j = 0; j < 16; ++j) {
        const uint key = (uint)__shfl((int)key_l, (lane & 48) + j);
        const int kidx = (int)(key & 1023u);
        const float4 cw = cb4[gbase + kidx * 16 + l15];
        out4[(size_t)(n0 + j) * 64 + lane] = cw;
    }

    #pragma unroll
    for (int m = 1; m <= 32; m <<= 1) lsum += __shfl_xor(lsum, m);
    if (lane == 0) part[wave] = lsum;
    __syncthreads();
    if (tid == 0)
        atomicAdd(loss, (part[0] + part[1] + part[2] + part[3]) * (1.25f / 8388608.0f));
}

extern "C" void kernel_launch(void* const* d_in, const int* in_sizes, int n_in,
                              void* d_out, int out_size, void* d_ws, size_t ws_size,
                              hipStream_t stream)
{
    const float* latents = (const float*)d_in[0];
    const float* cbg     = (const float*)d_in[1];
    float* out   = (float*)d_out;
    float* lossp = out + 8388608;

    // bf16 latents (16.8 MB) live in the front of d_out; emit overwrites after.
    uint*  lat_bf = (uint*)d_out;
    uint*  keys   = (uint*)d_ws;                       // 512 KB
    float* xsq_g  = (float*)d_ws + NTOT;               // 512 KB
    uint*  cb_bf  = (uint*)d_ws + 2 * NTOT;            // 512 KB
    float* initv  = (float*)d_ws + 2 * NTOT + (KCB * DIM / 2);  // 16 KB

    vq_prep <<<dim3(8208), dim3(256), 0, stream>>>(latents, cbg, lat_bf, cb_bf,
                                                   initv, keys, xsq_g, lossp);
    vq_score<<<dim3(8192), dim3(256), 0, stream>>>(lat_bf, cb_bf, initv, keys);
    vq_emit <<<dim3(512),  dim3(256), 0, stream>>>(keys, xsq_g, cbg, out, lossp);
}

// Round 6
// 130.561 us; speedup vs baseline: 1.6290x; 1.6290x over previous
//
#include <hip/hip_runtime.h>

#define GD    256
#define DIM   64
#define KCB   1024
#define KT    256   // codewords per tile
#define NROW  32768
#define NTOT  131072

typedef float floatx4 __attribute__((ext_vector_type(4)));
typedef __bf16 bf16x8 __attribute__((ext_vector_type(8)));
typedef unsigned int uint;

union ABu { bf16x8 v; __bf16 h[8]; uint4 u4; };

// ---------------------------------------------------------------------------
// Score: r3 structure, but 512-thread blocks -> 8 waves/SIMD (2x r3/r4).
// 33 KB LDS, <=64 VGPR (launch_bounds 512,8) -> 4 blocks/CU, 32 waves/CU.
// grid 2048 = g(2b) x chunk(7b) x tile(2b, fastest); 256 rows/block.
// ---------------------------------------------------------------------------
extern "C" __global__ void __launch_bounds__(512, 8)
vq_score(const float* __restrict__ latents, const float* __restrict__ cbg,
         uint* __restrict__ keys, float* __restrict__ xsq_g)
{
    __shared__ __attribute__((aligned(16))) uint cb_lds[KT * 32]; // 32 KB, XOR swizzled
    __shared__ float initv_lds[KT];

    const int tid  = threadIdx.x;
    const int wave = tid >> 6;
    const int lane = tid & 63;
    const int l15  = lane & 15;
    const int quad = lane >> 4;

    const int bid   = blockIdx.x;
    const int tile  = bid & 3;
    const int chunk = (bid >> 2) & 127;
    const int g     = bid >> 9;
    const int wRow0 = chunk * 256 + wave * 32;

    const float* __restrict__ cbgrp = cbg + (size_t)g * (KCB * DIM);

    // ---- A fragments first (latency overlaps staging): 32 rows/wave ----
    bf16x8 afrag[2][2];
    #pragma unroll
    for (int rt = 0; rt < 2; ++rt) {
        const int row = wRow0 + rt * 16 + l15;
        const float* src = latents + (size_t)row * GD + g * DIM + quad * 8;
        float xp = 0.f;
        #pragma unroll
        for (int ks = 0; ks < 2; ++ks) {
            float4 f0 = *(const float4*)(src + ks * 32);
            float4 f1 = *(const float4*)(src + ks * 32 + 4);
            xp += f0.x*f0.x + f0.y*f0.y + f0.z*f0.z + f0.w*f0.w
                + f1.x*f1.x + f1.y*f1.y + f1.z*f1.z + f1.w*f1.w;
            ABu a;
            a.h[0] = (__bf16)f0.x; a.h[1] = (__bf16)f0.y;
            a.h[2] = (__bf16)f0.z; a.h[3] = (__bf16)f0.w;
            a.h[4] = (__bf16)f1.x; a.h[5] = (__bf16)f1.y;
            a.h[6] = (__bf16)f1.z; a.h[7] = (__bf16)f1.w;
            afrag[rt][ks] = a.v;
        }
        xp += __shfl_xor(xp, 16);
        xp += __shfl_xor(xp, 32);
        if (tile == 0 && quad == 0)
            xsq_g[g * NROW + wRow0 + rt * 16 + l15] = xp;
    }

    // ---- stage 256-codeword tile (r3 strided scheme, half-row/thread) ----
    {
        const int kk   = tid >> 1;          // codeword row
        const int half = tid & 1;           // which 4 chunks of the row
        const float* src = cbgrp + (size_t)(tile * KT + kk) * DIM + half * 32;
        float d = 0.f;
        #pragma unroll
        for (int c = 0; c < 4; ++c) {
            float4 f0 = *(const float4*)(src + c * 8);
            float4 f1 = *(const float4*)(src + c * 8 + 4);
            d += f0.x*f0.x + f0.y*f0.y + f0.z*f0.z + f0.w*f0.w
               + f1.x*f1.x + f1.y*f1.y + f1.z*f1.z + f1.w*f1.w;
            ABu t;
            t.h[0] = (__bf16)f0.x; t.h[1] = (__bf16)f0.y;
            t.h[2] = (__bf16)f0.z; t.h[3] = (__bf16)f0.w;
            t.h[4] = (__bf16)f1.x; t.h[5] = (__bf16)f1.y;
            t.h[6] = (__bf16)f1.z; t.h[7] = (__bf16)f1.w;
            const int cc = half * 4 + c;
            const int dc = cc ^ (kk & 7);
            *(uint4*)&cb_lds[kk * 32 + dc * 4] = t.u4;
        }
        d += __shfl_xor(d, 1);              // combine the two half-rows
        if (half == 0) initv_lds[kk] = -0.5f * d - 0.5f;  // every score < 0
    }
    __syncthreads();

    uint best[2][4];
    #pragma unroll
    for (int rt = 0; rt < 2; ++rt)
        #pragma unroll
        for (int r = 0; r < 4; ++r) best[rt][r] = 0xFFFFFFFFu;

    #pragma unroll 2
    for (int t = 0; t < 16; ++t) {
        const int kkl = t * 16 + l15;
        const float v = initv_lds[kkl];
        ABu b0, b1;
        b0.u4 = *(const uint4*)&cb_lds[kkl * 32 + (((quad    ) ^ (kkl & 7)) << 2)];
        b1.u4 = *(const uint4*)&cb_lds[kkl * 32 + (((quad + 4) ^ (kkl & 7)) << 2)];
        const uint kcol = (uint)(tile * KT + kkl);
        const floatx4 accb = { v, v, v, v };   // shared C operand (D != C)
        #pragma unroll
        for (int rt = 0; rt < 2; ++rt) {
            floatx4 acc = __builtin_amdgcn_mfma_f32_16x16x32_bf16(afrag[rt][0], b0.v, accb, 0, 0, 0);
            acc = __builtin_amdgcn_mfma_f32_16x16x32_bf16(afrag[rt][1], b1.v, acc, 0, 0, 0);
            // score < 0 -> fp32 bits monotone decreasing; pack idx, min_u32
            #pragma unroll
            for (int r = 0; r < 4; ++r) {
                const uint key = (__float_as_uint(acc[r]) & 0xFFFFFC00u) | kcol;
                best[rt][r] = best[rt][r] < key ? best[rt][r] : key;
            }
        }
    }

    // ---- 16-lane column reduce, then cross-block atomicMin (4 tiles only) ----
    #pragma unroll
    for (int rt = 0; rt < 2; ++rt)
        #pragma unroll
        for (int r = 0; r < 4; ++r) {
            uint kmin = best[rt][r];
            #pragma unroll
            for (int m = 1; m <= 8; m <<= 1) {
                const uint o = (uint)__shfl_xor((int)kmin, m);
                kmin = o < kmin ? o : kmin;
            }
            if (l15 == 0)
                atomicMin(&keys[g * NROW + wRow0 + rt * 16 + quad * 4 + r], kmin);
        }
}

// ---------------------------------------------------------------------------
// Emit: wave = 16 rows x 4 groups (quad=group); dense 1 KB row writes.
// ---------------------------------------------------------------------------
extern "C" __global__ void __launch_bounds__(256, 4)
vq_emit(const uint* __restrict__ keys, const float* __restrict__ xsq_g,
        const float* __restrict__ cbg, float* __restrict__ out,
        float* __restrict__ loss)
{
    __shared__ float part[4];
    const int tid  = threadIdx.x;
    const int wave = tid >> 6;
    const int lane = tid & 63;
    const int l15  = lane & 15;
    const int quad = lane >> 4;          // group index (G == 4)
    const int n0   = blockIdx.x * 64 + wave * 16;

    const uint  key_l = keys [quad * NROW + n0 + l15];
    const float xsq_l = xsq_g[quad * NROW + n0 + l15];
    const float sc_l  = __uint_as_float(key_l & 0xFFFFFC00u);
    float lsum = xsq_l - 2.f * sc_l - 1.f;   // dist = x_sq - 2*score - 1

    const float4* __restrict__ cb4 = (const float4*)cbg;
    float4* __restrict__ out4 = (float4*)out;
    const int gbase = quad * (KCB * DIM / 4);
    #pragma unroll
    for (int j = 0; j < 16; ++j) {
        const uint key = (uint)__shfl((int)key_l, (lane & 48) + j);
        const int kidx = (int)(key & 1023u);
        const float4 cw = cb4[gbase + kidx * 16 + l15];
        out4[(size_t)(n0 + j) * 64 + lane] = cw;   // dense 1 KB per wave-instr
    }

    #pragma unroll
    for (int m = 1; m <= 32; m <<= 1) lsum += __shfl_xor(lsum, m);
    if (lane == 0) part[wave] = lsum;
    __syncthreads();
    if (tid == 0)
        atomicAdd(loss, (part[0] + part[1] + part[2] + part[3]) * (1.25f / 8388608.0f));
}

extern "C" void kernel_launch(void* const* d_in, const int* in_sizes, int n_in,
                              void* d_out, int out_size, void* d_ws, size_t ws_size,
                              hipStream_t stream)
{
    const float* latents = (const float*)d_in[0];
    const float* cbg     = (const float*)d_in[1];
    float* out   = (float*)d_out;
    float* lossp = out + 8388608;

    uint*  keys  = (uint*)d_ws;
    float* xsq_g = (float*)d_ws + NTOT;

    hipMemsetAsync(keys, 0xFF, NTOT * sizeof(uint), stream);
    hipMemsetAsync(lossp, 0, sizeof(float), stream);
    vq_score<<<dim3(2048), dim3(512), 0, stream>>>(latents, cbg, keys, xsq_g);
    vq_emit <<<dim3(512),  dim3(256), 0, stream>>>(keys, xsq_g, cbg, out, lossp);
}

// Round 7
// 129.628 us; speedup vs baseline: 1.6408x; 1.0072x over previous
//
#include <hip/hip_runtime.h>

#define GD    256
#define DIM   64
#define KCB   1024
#define KT    256   // codewords per tile
#define NROW  32768
#define NTOT  131072

typedef float floatx4 __attribute__((ext_vector_type(4)));
typedef __bf16 bf16x8 __attribute__((ext_vector_type(8)));
typedef unsigned int uint;

union ABu { bf16x8 v; __bf16 h[8]; uint4 u4; };
union P8u { __bf16 h[8]; uint4 u4; };

// ---------------------------------------------------------------------------
// Prep: latents fp32 -> bf16 rows [g][n][64] (plain layout) + x_sq;
// codebook fp32 -> bf16 rows with 16B-chunk XOR swizzle (LDS image) + initv;
// keys = ~0, loss = 0. Pure-BW kernel; all conversion VALU lives here.
// ---------------------------------------------------------------------------
extern "C" __global__ void __launch_bounds__(256)
vq_prep(const float* __restrict__ latents, const float* __restrict__ cbg,
        uint* __restrict__ lat_bf, uint* __restrict__ cb_bf,
        float* __restrict__ initv, uint* __restrict__ keys,
        float* __restrict__ xsq_g, float* __restrict__ loss)
{
    const int bid = blockIdx.x;
    const int tid = threadIdx.x;
    if (bid < 512) {                          // latents: thread = one (g,n) row
        const int g = tid >> 6;               // wave-uniform group
        const int n = bid * 64 + (tid & 63);
        const float4* __restrict__ src = (const float4*)latents + (size_t)n * 64 + g * 16;
        uint* __restrict__ drow = lat_bf + ((size_t)g * NROW + n) * 32;
        float xp = 0.f;
        #pragma unroll
        for (int c = 0; c < 8; ++c) {
            const float4 f0 = src[c * 2];
            const float4 f1 = src[c * 2 + 1];
            xp += f0.x*f0.x + f0.y*f0.y + f0.z*f0.z + f0.w*f0.w
                + f1.x*f1.x + f1.y*f1.y + f1.z*f1.z + f1.w*f1.w;
            P8u t;
            t.h[0]=(__bf16)f0.x; t.h[1]=(__bf16)f0.y; t.h[2]=(__bf16)f0.z; t.h[3]=(__bf16)f0.w;
            t.h[4]=(__bf16)f1.x; t.h[5]=(__bf16)f1.y; t.h[6]=(__bf16)f1.z; t.h[7]=(__bf16)f1.w;
            *(uint4*)&drow[c * 4] = t.u4;     // plain chunk order (global reads)
        }
        xsq_g[g * NROW + n] = xp;
        keys [g * NROW + n] = 0xFFFFFFFFu;
        if (bid == 0 && tid == 0) *loss = 0.f;
    } else {                                  // codebook: thread = one codeword
        const int k = (bid - 512) * 256 + tid;          // 0..4095 global row
        const float4* __restrict__ src = (const float4*)cbg + (size_t)k * 16;
        uint* __restrict__ drow = cb_bf + (size_t)k * 32;
        float csq = 0.f;
        #pragma unroll
        for (int c = 0; c < 8; ++c) {
            const float4 f0 = src[c * 2];
            const float4 f1 = src[c * 2 + 1];
            csq += f0.x*f0.x + f0.y*f0.y + f0.z*f0.z + f0.w*f0.w
                 + f1.x*f1.x + f1.y*f1.y + f1.z*f1.z + f1.w*f1.w;
            P8u t;
            t.h[0]=(__bf16)f0.x; t.h[1]=(__bf16)f0.y; t.h[2]=(__bf16)f0.z; t.h[3]=(__bf16)f0.w;
            t.h[4]=(__bf16)f1.x; t.h[5]=(__bf16)f1.y; t.h[6]=(__bf16)f1.z; t.h[7]=(__bf16)f1.w;
            const int dc = c ^ (k & 7);       // LDS-bank XOR swizzle baked in
            *(uint4*)&drow[dc * 4] = t.u4;
        }
        initv[k] = -0.5f * csq - 0.5f;        // makes every score < 0
    }
}

// ---------------------------------------------------------------------------
// Score: pure MFMA+argmin hot loop, zero cvt, zero per-iter address VALU.
// 256 thr (4 waves), 64 rows/wave, KT=256 tile DMA'd via global_load_lds.
// bid bits: clo(3) | tile(2) | chi(4) | g(2): tile-siblings are 8 apart ->
// same XCD (bid%8 round-robin) -> latent rows L2-shared across the 4 tiles.
// ---------------------------------------------------------------------------
extern "C" __global__ void __launch_bounds__(256, 4)
vq_score(const uint* __restrict__ lat_bf, const uint* __restrict__ cb_bf,
         const float* __restrict__ initv, uint* __restrict__ keys)
{
    __shared__ __attribute__((aligned(16))) uint  cb_lds[KT * 32];  // 32 KB image
    __shared__ __attribute__((aligned(16))) float iv_lds[KT];       // 1 KB

    const int tid  = threadIdx.x;
    const int wave = tid >> 6;
    const int lane = tid & 63;
    const int l15  = lane & 15;
    const int quad = lane >> 4;

    const int bid  = blockIdx.x;
    const int clo  = bid & 7;
    const int tile = (bid >> 3) & 3;
    const int chi  = (bid >> 5) & 15;
    const int g    = bid >> 9;
    const int chunk = chi * 8 + clo;               // 0..127
    const int wRow0 = chunk * 256 + wave * 64;

    // ---- async DMA: 32 KB pre-swizzled codebook tile + 1 KB initv ----
    {
        const uint* gsrc = cb_bf + (size_t)((g * 4 + tile) * KT) * 32;
        #pragma unroll
        for (int i = 0; i < 8; ++i) {
            const int off = wave * 2048 + i * 256;          // uint words
            __builtin_amdgcn_global_load_lds(
                (const __attribute__((address_space(1))) uint*)(gsrc + off + lane * 4),
                (__attribute__((address_space(3))) uint*)&cb_lds[off], 16, 0, 0);
        }
        if (wave == 0) {
            const uint* isrc = (const uint*)(initv + (g * 4 + tile) * KT);
            __builtin_amdgcn_global_load_lds(
                (const __attribute__((address_space(1))) uint*)(isrc + lane * 4),
                (__attribute__((address_space(3))) uint*)&iv_lds[0], 16, 0, 0);
        }
    }

    // ---- A fragments: direct bf16 16B loads, overlap the DMA ----
    bf16x8 afrag[4][2];
    const uint* abase = lat_bf + ((size_t)g * NROW + wRow0) * 32;
    #pragma unroll
    for (int rt = 0; rt < 4; ++rt)
        #pragma unroll
        for (int ks = 0; ks < 2; ++ks) {
            ABu a;
            a.u4 = *(const uint4*)&abase[(rt * 16 + l15) * 32 + (ks * 4 + quad) * 4];
            afrag[rt][ks] = a.v;
        }
    __syncthreads();

    uint best[4][4];
    #pragma unroll
    for (int rt = 0; rt < 4; ++rt)
        #pragma unroll
        for (int r = 0; r < 4; ++r) best[rt][r] = 0xFFFFFFFFu;

    // Hot loop: bases computed once; per-t addresses are immediate offsets
    // (t*2048 B) because kkl&7 == l15&7 is t-invariant.
    const uint*  bbase0 = &cb_lds[l15 * 32 + ((quad       ^ (l15 & 7)) << 2)];
    const uint*  bbase1 = &cb_lds[l15 * 32 + (((quad + 4) ^ (l15 & 7)) << 2)];
    const float* ivb    = &iv_lds[l15];
    const uint   kcol0  = (uint)(tile * KT + l15);

    #pragma unroll 4
    for (int t = 0; t < 16; ++t) {
        const float v = ivb[t * 16];
        ABu b0, b1;
        b0.u4 = *(const uint4*)(bbase0 + t * 512);
        b1.u4 = *(const uint4*)(bbase1 + t * 512);
        const uint kcol = kcol0 + t * 16;
        const floatx4 accb = { v, v, v, v };       // shared C operand (D != C)
        #pragma unroll
        for (int rt = 0; rt < 4; ++rt) {
            floatx4 acc = __builtin_amdgcn_mfma_f32_16x16x32_bf16(afrag[rt][0], b0.v, accb, 0, 0, 0);
            acc = __builtin_amdgcn_mfma_f32_16x16x32_bf16(afrag[rt][1], b1.v, acc, 0, 0, 0);
            // score < 0 -> fp32 bits monotone decreasing; pack idx, min_u32
            #pragma unroll
            for (int r = 0; r < 4; ++r) {
                const uint key = (__float_as_uint(acc[r]) & 0xFFFFFC00u) | kcol;
                best[rt][r] = best[rt][r] < key ? best[rt][r] : key;
            }
        }
    }

    // ---- 16-lane column reduce, then cross-block atomicMin (4 tiles) ----
    #pragma unroll
    for (int rt = 0; rt < 4; ++rt)
        #pragma unroll
        for (int r = 0; r < 4; ++r) {
            uint kmin = best[rt][r];
            #pragma unroll
            for (int m = 1; m <= 8; m <<= 1) {
                const uint o = (uint)__shfl_xor((int)kmin, m);
                kmin = o < kmin ? o : kmin;
            }
            if (l15 == 0)
                atomicMin(&keys[g * NROW + wRow0 + rt * 16 + quad * 4 + r], kmin);
        }
}

// ---------------------------------------------------------------------------
// Emit: wave = 16 rows x 4 groups (quad=group); dense 1 KB row writes.
// ---------------------------------------------------------------------------
extern "C" __global__ void __launch_bounds__(256, 4)
vq_emit(const uint* __restrict__ keys, const float* __restrict__ xsq_g,
        const float* __restrict__ cbg, float* __restrict__ out,
        float* __restrict__ loss)
{
    __shared__ float part[4];
    const int tid  = threadIdx.x;
    const int wave = tid >> 6;
    const int lane = tid & 63;
    const int l15  = lane & 15;
    const int quad = lane >> 4;          // group index (G == 4)
    const int n0   = blockIdx.x * 64 + wave * 16;

    const uint  key_l = keys [quad * NROW + n0 + l15];
    const float xsq_l = xsq_g[quad * NROW + n0 + l15];
    const float sc_l  = __uint_as_float(key_l & 0xFFFFFC00u);
    float lsum = xsq_l - 2.f * sc_l - 1.f;   // dist = x_sq - 2*score - 1

    const float4* __restrict__ cb4 = (const float4*)cbg;
    float4* __restrict__ out4 = (float4*)out;
    const int gbase = quad * (KCB * DIM / 4);
    #pragma unroll
    for (int j = 0; j < 16; ++j) {
        const uint key = (uint)__shfl((int)key_l, (lane & 48) + j);
        const int kidx = (int)(key & 1023u);
        const float4 cw = cb4[gbase + kidx * 16 + l15];
        out4[(size_t)(n0 + j) * 64 + lane] = cw;   // dense 1 KB per wave-instr
    }

    #pragma unroll
    for (int m = 1; m <= 32; m <<= 1) lsum += __shfl_xor(lsum, m);
    if (lane == 0) part[wave] = lsum;
    __syncthreads();
    if (tid == 0)
        atomicAdd(loss, (part[0] + part[1] + part[2] + part[3]) * (1.25f / 8388608.0f));
}

extern "C" void kernel_launch(void* const* d_in, const int* in_sizes, int n_in,
                              void* d_out, int out_size, void* d_ws, size_t ws_size,
                              hipStream_t stream)
{
    const float* latents = (const float*)d_in[0];
    const float* cbg     = (const float*)d_in[1];
    float* out   = (float*)d_out;
    float* lossp = out + 8388608;

    // bf16 latents (16.8 MB) live in the front of d_out; emit overwrites after.
    uint*  lat_bf = (uint*)d_out;
    uint*  keys   = (uint*)d_ws;                         // 512 KB
    float* xsq_g  = (float*)((uint*)d_ws + NTOT);        // 512 KB
    uint*  cb_bf  = (uint*)d_ws + 2 * NTOT;              // 4096*32 words = 512 KB
    float* initv  = (float*)((uint*)d_ws + 2 * NTOT + 131072);  // 16 KB (AFTER cb_bf!)

    vq_prep <<<dim3(528),  dim3(256), 0, stream>>>(latents, cbg, lat_bf, cb_bf,
                                                   initv, keys, xsq_g, lossp);
    vq_score<<<dim3(2048), dim3(256), 0, stream>>>(lat_bf, cb_bf, initv, keys);
    vq_emit <<<dim3(512),  dim3(256), 0, stream>>>(keys, xsq_g, cbg, out, lossp);
}